// Round 1
// baseline (111.485 us; speedup 1.0000x reference)
//
#include <hip/hip_runtime.h>

#define NBLK 32
#define OPB  4      // h-outputs per block: 32*4 = 128
#define TPB  256

__device__ __forceinline__ float relu_(float x) { return fmaxf(x, 0.f); }

__global__ void init_ws_kernel(int* cnt) {
    if (threadIdx.x < 16) cnt[threadIdx.x] = 0;
}

__launch_bounds__(TPB, 1)
__global__ void actor_kernel(
    const float* __restrict__ inp,
    const float* __restrict__ conv_w, const float* __restrict__ conv_b,
    const float* __restrict__ w0, const float* __restrict__ b0,
    const float* __restrict__ w1, const float* __restrict__ b1,
    const float* __restrict__ w2, const float* __restrict__ b2,
    const float* __restrict__ w3, const float* __restrict__ b3,
    const float* __restrict__ w4, const float* __restrict__ b4,
    float* __restrict__ out, int* __restrict__ cnt,
    float* __restrict__ partials)
{
    const int tid = threadIdx.x;
    const int b   = blockIdx.x;

    __shared__ __align__(16) float lw3[OPB * 2048];   // 32 KB slice, resident all 7 steps
    __shared__ __align__(16) float lfeat[2048];
    __shared__ __align__(16) float lcw[512];
    __shared__ float lcb[128];
    __shared__ float lw0[128], lb0[128], lw1[128], lb1[128], lw2v[128], lb2[128];
    __shared__ float lb3[128];
    __shared__ float lw4[768];
    __shared__ float lb4[8];
    __shared__ float st2[8], st3[8], st4[8];
    __shared__ float sx[8];      // 0:x0  1:x1  2:x5  3:s40  4:vs
    __shared__ float lbw[8];
    __shared__ float h_lds[OPB];
    __shared__ float logits_l[8];

    // ---- one-time staging ----
    {
        const float4* g = (const float4*)(w3 + b * OPB * 2048);
        float4* l = (float4*)lw3;
        #pragma unroll
        for (int idx = tid; idx < OPB * 2048 / 4; idx += TPB) l[idx] = g[idx];
    }
    for (int idx = tid; idx < 512; idx += TPB) lcw[idx] = conv_w[idx];
    if (tid < 128) {
        lcb[tid] = conv_b[tid];
        lw0[tid] = w0[tid];  lb0[tid] = b0[tid];
        lw1[tid] = w1[tid];  lb1[tid] = b1[tid];
        lw2v[tid] = w2[tid]; lb2[tid] = b2[tid];
        lb3[tid] = b3[tid];
    }
    for (int idx = tid; idx < 768; idx += TPB) lw4[idx] = w4[idx];
    if (tid < 6) lb4[tid] = b4[tid];
    if (tid < 8) {
        st2[tid] = inp[16 + tid];
        st3[tid] = inp[24 + tid];
        st4[tid] = inp[32 + tid];
        lbw[tid] = inp[48 + tid];
    }
    if (tid == 0) {
        sx[0] = inp[7];    // st[0,7]
        sx[1] = inp[15];   // st[1,7]
        sx[2] = inp[39];   // st[4,7]
        sx[3] = inp[32];   // st[4,0]
        sx[4] = inp[56];   // vs = inp[7,0]
    }
    __syncthreads();

    const int wv = tid >> 6, lane = tid & 63;

    for (int i = 0; i < 7; ++i) {
        // ---- feat into LDS ----
        if (tid < 128) {
            lfeat[tid]        = relu_(sx[0] * lw0[tid] + lb0[tid]);     // s0
            lfeat[1920 + tid] =        sx[2] * lw2v[tid] + lb2[tid];    // s5 (no relu)
        } else {
            int j = tid - 128;
            lfeat[128 + j] = relu_(sx[1] * lw1[j] + lb1[j]);            // s1
        }
        for (int m = tid; m < 640; m += TPB) {                          // s2, s3
            int c = m / 5, w = m - c * 5;
            float a2 = lcb[c], a3 = lcb[c];
            #pragma unroll
            for (int k = 0; k < 4; ++k) {
                float cw = lcw[c * 4 + k];
                a2 += st2[w + k] * cw;
                a3 += st3[w + k] * cw;
            }
            lfeat[256 + m] = relu_(a2);
            lfeat[896 + m] = relu_(a3);
        }
        for (int m = tid; m < 384; m += TPB) {                          // s4
            int c = m / 3, w = m - c * 3;
            float a4 = lcb[c];
            #pragma unroll
            for (int k = 0; k < 4; ++k) a4 += st4[w + k] * lcw[c * 4 + k];
            lfeat[1536 + m] = relu_(a4);
        }
        __syncthreads();

        // ---- h slice: wave wv computes h[b*4+wv] ----
        {
            const float4* wrow = (const float4*)(lw3 + wv * 2048);
            const float4* frow = (const float4*)lfeat;
            float4 acc = make_float4(0.f, 0.f, 0.f, 0.f);
            #pragma unroll
            for (int it = 0; it < 8; ++it) {
                float4 a = wrow[it * 64 + lane];
                float4 f = frow[it * 64 + lane];
                acc.x += a.x * f.x; acc.y += a.y * f.y;
                acc.z += a.z * f.z; acc.w += a.w * f.w;
            }
            float s = (acc.x + acc.y) + (acc.z + acc.w);
            #pragma unroll
            for (int off = 32; off > 0; off >>= 1) s += __shfl_xor(s, off);
            if (lane == 0) h_lds[wv] = relu_(s + lb3[b * OPB + wv]);
        }
        __syncthreads();

        // ---- partial logits -> global slot ----
        if (tid < 6) {
            float p = 0.f;
            #pragma unroll
            for (int w = 0; w < OPB; ++w) p += lw4[tid * 128 + b * OPB + w] * h_lds[w];
            __hip_atomic_store(&partials[(i * NBLK + b) * 8 + tid], p,
                               __ATOMIC_RELAXED, __HIP_MEMORY_SCOPE_AGENT);
        }
        __syncthreads();

        // ---- one device-scope sync per step ----
        if (tid == 0) {
            __threadfence();
            __hip_atomic_fetch_add(&cnt[i], 1, __ATOMIC_RELEASE, __HIP_MEMORY_SCOPE_AGENT);
            if (i < 6 || b == 0) {
                while (__hip_atomic_load(&cnt[i], __ATOMIC_ACQUIRE,
                                         __HIP_MEMORY_SCOPE_AGENT) < NBLK)
                    __builtin_amdgcn_s_sleep(1);
                __threadfence();
            }
        }
        __syncthreads();

        if (i < 6) {
            // every block reduces logits locally -> identical argmax everywhere
            if (tid < 6) {
                float p = lb4[tid];
                #pragma unroll
                for (int bb = 0; bb < NBLK; ++bb)
                    p += __hip_atomic_load(&partials[(i * NBLK + bb) * 8 + tid],
                                           __ATOMIC_RELAXED, __HIP_MEMORY_SCOPE_AGENT);
                logits_l[tid] = p;
            }
            __syncthreads();
            if (tid == 0) {
                const float VBRc[6] = {300.f, 750.f, 1200.f, 1850.f, 2850.f, 4300.f};
                float best = logits_l[0]; int a = 0;
                #pragma unroll
                for (int r = 1; r < 6; ++r) {
                    float v = logits_l[r];
                    if (v > best) { best = v; a = r; }
                }
                float vs    = sx[4];
                float vca   = vs * (float)(1 << a);
                float delay = vca / lbw[i] - 30000.f;
                sx[0] = VBRc[a] * (1.f / 4300.f);      // st[0,7]
                sx[1] = 3.0f;                          // st[1,7] = 30000/1000/10
                #pragma unroll
                for (int c = 0; c < 7; ++c) { st2[c] = st2[c + 1]; st3[c] = st3[c + 1]; }
                st2[7] = vca / delay * 1e-3f;
                st3[7] = delay * 1e-4f;
                sx[2] = sx[3];                         // new st[4,7] = old st[4,0]
                sx[3] = vs * 1e-6f;                    // st[4,0] after set
                #pragma unroll
                for (int j = 0; j < 6; ++j) st4[j] = vs * (float)(1 << j) * 1e-6f;
            }
            __syncthreads();
        } else if (b == 0) {
            if (tid < 6) {
                float p = lb4[tid];
                #pragma unroll
                for (int bb = 0; bb < NBLK; ++bb)
                    p += __hip_atomic_load(&partials[(6 * NBLK + bb) * 8 + tid],
                                           __ATOMIC_RELAXED, __HIP_MEMORY_SCOPE_AGENT);
                out[tid] = p;
            }
        }
    }
}

extern "C" void kernel_launch(void* const* d_in, const int* in_sizes, int n_in,
                              void* d_out, int out_size, void* d_ws, size_t ws_size,
                              hipStream_t stream) {
    const float* inp    = (const float*)d_in[0];
    const float* conv_w = (const float*)d_in[1];
    const float* conv_b = (const float*)d_in[2];
    const float* w0     = (const float*)d_in[3];
    const float* b0     = (const float*)d_in[4];
    const float* w1     = (const float*)d_in[5];
    const float* b1     = (const float*)d_in[6];
    const float* w2     = (const float*)d_in[7];
    const float* b2     = (const float*)d_in[8];
    const float* w3     = (const float*)d_in[9];
    const float* b3     = (const float*)d_in[10];
    const float* w4     = (const float*)d_in[11];
    const float* b4     = (const float*)d_in[12];

    int*   cnt      = (int*)d_ws;
    float* partials = (float*)((char*)d_ws + 64);

    init_ws_kernel<<<1, 64, 0, stream>>>(cnt);
    actor_kernel<<<NBLK, TPB, 0, stream>>>(inp, conv_w, conv_b,
                                           w0, b0, w1, b1, w2, b2,
                                           w3, b3, w4, b4,
                                           (float*)d_out, cnt, partials);
}

// Round 2
// 103.212 us; speedup vs baseline: 1.0802x; 1.0802x over previous
//
#include <hip/hip_runtime.h>

#define NBLK 32
#define OPB  4      // h-outputs per block: 32*4 = 128
#define TPB  256
#define FSTRIDE 32  // flag spacing in ints = 128 B, one cacheline per block

__device__ __forceinline__ float relu_(float x) { return fmaxf(x, 0.f); }

// Sync design: block b publishes step-i results, then release-stores
// flags[b*FSTRIDE] = i+1 (monotone 1..7). Waiters spin with >= compare.
// Poison 0xAAAAAAAA is negative as int -> no init kernel needed.

__launch_bounds__(TPB, 1)
__global__ void actor_kernel(
    const float* __restrict__ inp,
    const float* __restrict__ conv_w, const float* __restrict__ conv_b,
    const float* __restrict__ w0, const float* __restrict__ b0,
    const float* __restrict__ w1, const float* __restrict__ b1,
    const float* __restrict__ w2, const float* __restrict__ b2,
    const float* __restrict__ w3, const float* __restrict__ b3,
    const float* __restrict__ w4, const float* __restrict__ b4,
    float* __restrict__ out, int* __restrict__ flags,
    float* __restrict__ partials)
{
    const int tid = threadIdx.x;
    const int b   = blockIdx.x;

    __shared__ __align__(16) float lw3[OPB * 2048];   // 32 KB slice, resident all 7 steps
    __shared__ __align__(16) float lfeat[2048];
    __shared__ __align__(16) float lcw[512];
    __shared__ float lcb[128];
    __shared__ float lw0[128], lb0[128], lw1[128], lb1[128], lw2v[128], lb2[128];
    __shared__ float lb3[128];
    __shared__ float lw4[768];
    __shared__ float lb4[8];
    __shared__ float st2[8], st3[8], st4[8];
    __shared__ float sx[8];      // 0:x0  1:x1  2:x5  3:s40  4:vs
    __shared__ float lbw[8];
    __shared__ float h_lds[OPB];
    __shared__ float logits_l[8];

    // ---- one-time staging ----
    {
        const float4* g = (const float4*)(w3 + b * OPB * 2048);
        float4* l = (float4*)lw3;
        #pragma unroll
        for (int idx = tid; idx < OPB * 2048 / 4; idx += TPB) l[idx] = g[idx];
    }
    for (int idx = tid; idx < 512; idx += TPB) lcw[idx] = conv_w[idx];
    if (tid < 128) {
        lcb[tid] = conv_b[tid];
        lw0[tid] = w0[tid];  lb0[tid] = b0[tid];
        lw1[tid] = w1[tid];  lb1[tid] = b1[tid];
        lw2v[tid] = w2[tid]; lb2[tid] = b2[tid];
        lb3[tid] = b3[tid];
    }
    for (int idx = tid; idx < 768; idx += TPB) lw4[idx] = w4[idx];
    if (tid < 6) lb4[tid] = b4[tid];
    if (tid < 8) {
        st2[tid] = inp[16 + tid];
        st3[tid] = inp[24 + tid];
        st4[tid] = inp[32 + tid];
        lbw[tid] = inp[48 + tid];
    }
    if (tid == 0) {
        sx[0] = inp[7];    // st[0,7]
        sx[1] = inp[15];   // st[1,7]
        sx[2] = inp[39];   // st[4,7]
        sx[3] = inp[32];   // st[4,0]
        sx[4] = inp[56];   // vs = inp[7,0]
    }
    __syncthreads();

    const int wv = tid >> 6, lane = tid & 63;

    for (int i = 0; i < 7; ++i) {
        // ---- feat into LDS ----
        if (tid < 128) {
            lfeat[tid]        = relu_(sx[0] * lw0[tid] + lb0[tid]);     // s0
            lfeat[1920 + tid] =        sx[2] * lw2v[tid] + lb2[tid];    // s5 (no relu)
        } else {
            int j = tid - 128;
            lfeat[128 + j] = relu_(sx[1] * lw1[j] + lb1[j]);            // s1
        }
        for (int m = tid; m < 640; m += TPB) {                          // s2, s3
            int c = m / 5, w = m - c * 5;
            float a2 = lcb[c], a3 = lcb[c];
            #pragma unroll
            for (int k = 0; k < 4; ++k) {
                float cw = lcw[c * 4 + k];
                a2 += st2[w + k] * cw;
                a3 += st3[w + k] * cw;
            }
            lfeat[256 + m] = relu_(a2);
            lfeat[896 + m] = relu_(a3);
        }
        for (int m = tid; m < 384; m += TPB) {                          // s4
            int c = m / 3, w = m - c * 3;
            float a4 = lcb[c];
            #pragma unroll
            for (int k = 0; k < 4; ++k) a4 += st4[w + k] * lcw[c * 4 + k];
            lfeat[1536 + m] = relu_(a4);
        }
        __syncthreads();

        // ---- h slice: wave wv computes h[b*4+wv] ----
        {
            const float4* wrow = (const float4*)(lw3 + wv * 2048);
            const float4* frow = (const float4*)lfeat;
            float4 acc = make_float4(0.f, 0.f, 0.f, 0.f);
            #pragma unroll
            for (int it = 0; it < 8; ++it) {
                float4 a = wrow[it * 64 + lane];
                float4 f = frow[it * 64 + lane];
                acc.x += a.x * f.x; acc.y += a.y * f.y;
                acc.z += a.z * f.z; acc.w += a.w * f.w;
            }
            float s = (acc.x + acc.y) + (acc.z + acc.w);
            #pragma unroll
            for (int off = 32; off > 0; off >>= 1) s += __shfl_xor(s, off);
            if (lane == 0) h_lds[wv] = relu_(s + lb3[b * OPB + wv]);
        }
        __syncthreads();

        // ---- partial logits -> per-block global slot, then release flag ----
        if (tid < 6) {
            float p = 0.f;
            #pragma unroll
            for (int w = 0; w < OPB; ++w) p += lw4[tid * 128 + b * OPB + w] * h_lds[w];
            __hip_atomic_store(&partials[(i * NBLK + b) * 8 + tid], p,
                               __ATOMIC_RELAXED, __HIP_MEMORY_SCOPE_AGENT);
        }
        __syncthreads();          // all partial stores issued before flag
        if (tid == 0)
            __hip_atomic_store(&flags[b * FSTRIDE], i + 1,
                               __ATOMIC_RELEASE, __HIP_MEMORY_SCOPE_AGENT);

        // ---- parallel wait: lane t polls block t's flag ----
        if (i < 6 || b == 0) {
            if (tid < NBLK) {
                while (__hip_atomic_load(&flags[tid * FSTRIDE], __ATOMIC_ACQUIRE,
                                         __HIP_MEMORY_SCOPE_AGENT) < i + 1)
                    __builtin_amdgcn_s_sleep(1);
            }
        }
        __syncthreads();

        if (i < 6) {
            // every block reduces logits locally -> identical argmax everywhere
            if (tid < 6) {
                float p = lb4[tid];
                #pragma unroll
                for (int bb = 0; bb < NBLK; ++bb)
                    p += __hip_atomic_load(&partials[(i * NBLK + bb) * 8 + tid],
                                           __ATOMIC_RELAXED, __HIP_MEMORY_SCOPE_AGENT);
                logits_l[tid] = p;
            }
            __syncthreads();
            if (tid == 0) {
                const float VBRc[6] = {300.f, 750.f, 1200.f, 1850.f, 2850.f, 4300.f};
                float best = logits_l[0]; int a = 0;
                #pragma unroll
                for (int r = 1; r < 6; ++r) {
                    float v = logits_l[r];
                    if (v > best) { best = v; a = r; }
                }
                float vs    = sx[4];
                float vca   = vs * (float)(1 << a);
                float delay = vca / lbw[i] - 30000.f;
                sx[0] = VBRc[a] * (1.f / 4300.f);      // st[0,7]
                sx[1] = 3.0f;                          // st[1,7] = 30000/1000/10
                #pragma unroll
                for (int c = 0; c < 7; ++c) { st2[c] = st2[c + 1]; st3[c] = st3[c + 1]; }
                st2[7] = vca / delay * 1e-3f;
                st3[7] = delay * 1e-4f;
                sx[2] = sx[3];                         // new st[4,7] = old st[4,0]
                sx[3] = vs * 1e-6f;                    // st[4,0] after set
                #pragma unroll
                for (int j = 0; j < 6; ++j) st4[j] = vs * (float)(1 << j) * 1e-6f;
            }
            __syncthreads();
        } else if (b == 0) {
            if (tid < 6) {
                float p = lb4[tid];
                #pragma unroll
                for (int bb = 0; bb < NBLK; ++bb)
                    p += __hip_atomic_load(&partials[(6 * NBLK + bb) * 8 + tid],
                                           __ATOMIC_RELAXED, __HIP_MEMORY_SCOPE_AGENT);
                out[tid] = p;
            }
        }
    }
}

extern "C" void kernel_launch(void* const* d_in, const int* in_sizes, int n_in,
                              void* d_out, int out_size, void* d_ws, size_t ws_size,
                              hipStream_t stream) {
    const float* inp    = (const float*)d_in[0];
    const float* conv_w = (const float*)d_in[1];
    const float* conv_b = (const float*)d_in[2];
    const float* w0     = (const float*)d_in[3];
    const float* b0     = (const float*)d_in[4];
    const float* w1     = (const float*)d_in[5];
    const float* b1     = (const float*)d_in[6];
    const float* w2     = (const float*)d_in[7];
    const float* b2     = (const float*)d_in[8];
    const float* w3     = (const float*)d_in[9];
    const float* b3     = (const float*)d_in[10];
    const float* w4     = (const float*)d_in[11];
    const float* b4     = (const float*)d_in[12];

    int*   flags    = (int*)d_ws;                       // 32 flags, 128 B apart
    float* partials = (float*)((char*)d_ws + 8192);

    actor_kernel<<<NBLK, TPB, 0, stream>>>(inp, conv_w, conv_b,
                                           w0, b0, w1, b1, w2, b2,
                                           w3, b3, w4, b4,
                                           (float*)d_out, flags, partials);
}

// Round 3
// 99.946 us; speedup vs baseline: 1.1155x; 1.0327x over previous
//
#include <hip/hip_runtime.h>

#define NBLK 32
#define TPB  256
#define FSTRIDE 32   // flag spacing in ints (128 B)
#define PSTRIDE 64   // publish slot stride in floats (256 B)

__device__ __forceinline__ float relu_(float x) { return fmaxf(x, 0.f); }

// 2-step speculative grid-sync design:
//  group g handles steps i=2g, i+1. Each block publishes step-i partial
//  logits AND 6 candidate step-(i+1) partial logits (speculating over a_i).
//  One device-scope sync per group resolves BOTH argmaxes. 3 groups + final
//  eval = 4 syncs instead of 7.
//  Flags: block b release-stores flags[b*FSTRIDE] = g+1 (monotone 1..4);
//  poison 0xAAAAAAAA is negative as int -> no init kernel needed.

__launch_bounds__(TPB, 1)
__global__ void actor_kernel(
    const float* __restrict__ inp,
    const float* __restrict__ conv_w, const float* __restrict__ conv_b,
    const float* __restrict__ w0, const float* __restrict__ b0,
    const float* __restrict__ w1, const float* __restrict__ b1,
    const float* __restrict__ w2, const float* __restrict__ b2,
    const float* __restrict__ w3, const float* __restrict__ b3,
    const float* __restrict__ w4, const float* __restrict__ b4,
    float* __restrict__ out, int* __restrict__ flags,
    float* __restrict__ partials)
{
    const int tid = threadIdx.x;
    const int b   = blockIdx.x;

    __shared__ __align__(16) float lw3[4 * 2048];    // 32 KB row slice
    __shared__ __align__(16) float lfeat[2048];
    __shared__ __align__(16) float lc2[512], lc3[512]; // next-step common conv feats
    __shared__ float lbase2[128], lbase3[128], ls5[128];
    __shared__ float ls0[6 * 128];                   // 6 s0 variants (constant)
    __shared__ float ltmp[512];                      // s1c (128) + s4c (384), constant
    __shared__ __align__(16) float lcw[512];
    __shared__ float lcb[128];
    __shared__ float lw0v[128], lb0v[128], lw1v[128], lb1v[128];
    __shared__ float lw2v[128], lb2v[128], lb3v[128];
    __shared__ float lw4[768], lb4v[8];
    __shared__ float st2[8], st3[8], st4[8];
    __shared__ float sx[8];     // 0:st[0,7] 1:st[1,7] 2:st[4,7] 3:st[4,0] 4:vs
    __shared__ float lbw[8];
    __shared__ float h_lds[4], hv_lds[4 * 8];
    __shared__ float red[48];

    // ---- one-time staging ----
    {
        const float4* g4 = (const float4*)(w3 + b * 4 * 2048);
        float4* l4 = (float4*)lw3;
        for (int idx = tid; idx < 2048; idx += TPB) l4[idx] = g4[idx];
    }
    for (int idx = tid; idx < 512; idx += TPB) lcw[idx] = conv_w[idx];
    if (tid < 128) {
        lcb[tid]  = conv_b[tid];
        lw0v[tid] = w0[tid]; lb0v[tid] = b0[tid];
        lw1v[tid] = w1[tid]; lb1v[tid] = b1[tid];
        lw2v[tid] = w2[tid]; lb2v[tid] = b2[tid];
        lb3v[tid] = b3[tid];
    }
    for (int idx = tid; idx < 768; idx += TPB) lw4[idx] = w4[idx];
    if (tid < 6) lb4v[tid] = b4[tid];
    if (tid < 8) {
        st2[tid] = inp[16 + tid];
        st3[tid] = inp[24 + tid];
        st4[tid] = inp[32 + tid];
        lbw[tid] = inp[48 + tid];
    }
    if (tid == 0) {
        sx[0] = inp[7];   sx[1] = inp[15];
        sx[2] = inp[39];  sx[3] = inp[32];
        sx[4] = inp[56];
    }
    __syncthreads();

    // ---- constant-across-steps speculative feats ----
    if (tid < 128) {
        const float vb[6] = {300.f, 750.f, 1200.f, 1850.f, 2850.f, 4300.f};
        #pragma unroll
        for (int v = 0; v < 6; ++v)
            ls0[v * 128 + tid] = relu_(vb[v] * (1.f / 4300.f) * lw0v[tid] + lb0v[tid]);
        ltmp[tid] = relu_(3.0f * lw1v[tid] + lb1v[tid]);       // s1 after any update
    }
    for (int m = tid; m < 384; m += TPB) {                     // s4 after any update
        int c = m / 3, w = m - c * 3;
        float a = lcb[c];
        #pragma unroll
        for (int k = 0; k < 4; ++k)
            a += sx[4] * (float)(1 << (w + k)) * 1e-6f * lcw[c * 4 + k];
        ltmp[128 + m] = relu_(a);
    }
    __syncthreads();

    const int wv = tid >> 6, lane = tid & 63;
    const float* wr = lw3 + wv * 2048;                          // this wave's w3 row
    const float bias3 = lb3v[b * 4 + wv];

    // per-lane constant dot-partials: hs0p[v] (s0 variants), hs14p (s1+s4)
    float hs0p[6], hs14p;
    #pragma unroll
    for (int v = 0; v < 6; ++v)
        hs0p[v] = wr[lane] * ls0[v * 128 + lane] + wr[64 + lane] * ls0[v * 128 + 64 + lane];
    hs14p = wr[128 + lane] * ltmp[lane] + wr[192 + lane] * ltmp[64 + lane];
    #pragma unroll
    for (int k = 0; k < 6; ++k) {
        int m = lane + 64 * k;
        hs14p += wr[1536 + m] * ltmp[128 + m];
    }

    const float VBRc[6] = {300.f, 750.f, 1200.f, 1850.f, 2850.f, 4300.f};

    for (int g = 0; g < 3; ++g) {
        const int i = 2 * g;

        // ---- Phase A: feat_i (exact) + next-step common pieces ----
        if (tid < 128) {
            lfeat[tid]        = relu_(sx[0] * lw0v[tid] + lb0v[tid]);   // s0
            lfeat[1920 + tid] =        sx[2] * lw2v[tid] + lb2v[tid];   // s5 (no relu)
            lbase2[tid] = st2[5] * lcw[tid*4] + st2[6] * lcw[tid*4+1]
                        + st2[7] * lcw[tid*4+2] + lcb[tid];
            lbase3[tid] = st3[5] * lcw[tid*4] + st3[6] * lcw[tid*4+1]
                        + st3[7] * lcw[tid*4+2] + lcb[tid];
            ls5[tid] = sx[3] * lw2v[tid] + lb2v[tid];                   // next s5
        } else {
            int j = tid - 128;
            lfeat[128 + j] = relu_(sx[1] * lw1v[j] + lb1v[j]);          // s1
        }
        for (int m = tid; m < 640; m += TPB) {                          // s2, s3
            int c = m / 5, w = m - c * 5;
            float a2 = lcb[c], a3 = lcb[c];
            #pragma unroll
            for (int k = 0; k < 4; ++k) {
                float cw = lcw[c * 4 + k];
                a2 += st2[w + k] * cw;
                a3 += st3[w + k] * cw;
            }
            lfeat[256 + m] = relu_(a2);
            lfeat[896 + m] = relu_(a3);
        }
        for (int m = tid; m < 384; m += TPB) {                          // s4
            int c = m / 3, w = m - c * 3;
            float a4 = lcb[c];
            #pragma unroll
            for (int k = 0; k < 4; ++k) a4 += st4[w + k] * lcw[c * 4 + k];
            lfeat[1536 + m] = relu_(a4);
        }
        for (int m = tid; m < 512; m += TPB) {       // next-step s2/s3 windows 0..3
            int c = m >> 2, w = m & 3;
            float a2 = lcb[c], a3 = lcb[c];
            #pragma unroll
            for (int k = 0; k < 4; ++k) {
                float cw = lcw[c * 4 + k];
                a2 += st2[w + 1 + k] * cw;
                a3 += st3[w + 1 + k] * cw;
            }
            lc2[m] = relu_(a2);
            lc3[m] = relu_(a3);
        }
        __syncthreads();

        // ---- Phase B: wave dots ----
        float acc_i;
        {
            const float4* w4p = (const float4*)wr;
            const float4* f4p = (const float4*)lfeat;
            float4 acc = make_float4(0.f, 0.f, 0.f, 0.f);
            #pragma unroll
            for (int it = 0; it < 8; ++it) {
                float4 a = w4p[it * 64 + lane];
                float4 f = f4p[it * 64 + lane];
                acc.x += a.x * f.x; acc.y += a.y * f.y;
                acc.z += a.z * f.z; acc.w += a.w * f.w;
            }
            acc_i = (acc.x + acc.y) + (acc.z + acc.w);
        }

        float acc_c = hs14p
                    + wr[1920 + lane] * ls5[lane]
                    + wr[1984 + lane] * ls5[64 + lane];
        #pragma unroll
        for (int k = 0; k < 8; ++k) {
            int m = lane + 64 * k;
            int col = 256 + (m >> 2) * 5 + (m & 3);
            acc_c += wr[col] * lc2[m] + wr[640 + col] * lc3[m];
        }

        float n2[6], n3[6];
        {
            float bwi = lbw[i], vs = sx[4];
            #pragma unroll
            for (int v = 0; v < 6; ++v) {
                float vca   = vs * (float)(1 << v);
                float delay = vca / bwi - 30000.f;
                n2[v] = vca / delay * 1e-3f;
                n3[v] = delay * 1e-4f;
            }
        }
        float accv[6];
        #pragma unroll
        for (int v = 0; v < 6; ++v) accv[v] = hs0p[v];
        #pragma unroll
        for (int t = 0; t < 2; ++t) {
            int c = lane + 64 * t;
            float cw3 = lcw[c * 4 + 3];
            float bb2 = lbase2[c], bb3 = lbase3[c];
            float wc2 = wr[256 + c * 5 + 4], wc3 = wr[896 + c * 5 + 4];
            #pragma unroll
            for (int v = 0; v < 6; ++v)
                accv[v] += relu_(bb2 + n2[v] * cw3) * wc2
                         + relu_(bb3 + n3[v] * cw3) * wc3;
        }

        #pragma unroll
        for (int off = 32; off > 0; off >>= 1) {
            acc_i += __shfl_xor(acc_i, off);
            acc_c += __shfl_xor(acc_c, off);
            #pragma unroll
            for (int v = 0; v < 6; ++v) accv[v] += __shfl_xor(accv[v], off);
        }
        if (lane == 0) {
            h_lds[wv] = relu_(acc_i + bias3);
            #pragma unroll
            for (int v = 0; v < 6; ++v)
                hv_lds[wv * 8 + v] = relu_(acc_c + accv[v] + bias3);
        }
        __syncthreads();

        // ---- Phase C: publish 42 partial logits + flag ----
        if (tid < 42) {
            int q = tid / 6, t = tid - q * 6;
            float p = 0.f;
            if (q == 0) {
                #pragma unroll
                for (int w = 0; w < 4; ++w) p += lw4[t * 128 + b * 4 + w] * h_lds[w];
            } else {
                #pragma unroll
                for (int w = 0; w < 4; ++w) p += lw4[t * 128 + b * 4 + w] * hv_lds[w * 8 + (q - 1)];
            }
            __hip_atomic_store(&partials[(g * NBLK + b) * PSTRIDE + tid], p,
                               __ATOMIC_RELAXED, __HIP_MEMORY_SCOPE_AGENT);
        }
        __syncthreads();
        if (tid == 0)
            __hip_atomic_store(&flags[b * FSTRIDE], g + 1,
                               __ATOMIC_RELEASE, __HIP_MEMORY_SCOPE_AGENT);
        if (tid < NBLK) {
            while (__hip_atomic_load(&flags[tid * FSTRIDE], __ATOMIC_ACQUIRE,
                                     __HIP_MEMORY_SCOPE_AGENT) < g + 1)
                __builtin_amdgcn_s_sleep(1);
        }
        __syncthreads();

        // ---- Phase D: fan-in reduce, double argmax, double state update ----
        if (tid < 42) {
            float p = lb4v[tid % 6];
            #pragma unroll
            for (int bb = 0; bb < NBLK; ++bb)
                p += __hip_atomic_load(&partials[(g * NBLK + bb) * PSTRIDE + tid],
                                       __ATOMIC_RELAXED, __HIP_MEMORY_SCOPE_AGENT);
            red[tid] = p;
        }
        __syncthreads();
        if (tid == 0) {
            float best = red[0]; int a0 = 0;
            #pragma unroll
            for (int r = 1; r < 6; ++r) if (red[r] > best) { best = red[r]; a0 = r; }
            best = red[6 + 6 * a0]; int a1 = 0;
            #pragma unroll
            for (int r = 1; r < 6; ++r)
                if (red[6 + 6 * a0 + r] > best) { best = red[6 + 6 * a0 + r]; a1 = r; }

            // update(i, a0)
            {
                float vca = sx[4] * (float)(1 << a0);
                float delay = vca / lbw[i] - 30000.f;
                sx[0] = VBRc[a0] * (1.f / 4300.f);
                sx[1] = 3.0f;
                #pragma unroll
                for (int c = 0; c < 7; ++c) { st2[c] = st2[c + 1]; st3[c] = st3[c + 1]; }
                st2[7] = vca / delay * 1e-3f;
                st3[7] = delay * 1e-4f;
                sx[2] = sx[3]; sx[3] = sx[4] * 1e-6f;
                #pragma unroll
                for (int j = 0; j < 6; ++j) st4[j] = sx[4] * (float)(1 << j) * 1e-6f;
            }
            // update(i+1, a1)
            {
                float vca = sx[4] * (float)(1 << a1);
                float delay = vca / lbw[i + 1] - 30000.f;
                sx[0] = VBRc[a1] * (1.f / 4300.f);
                sx[1] = 3.0f;
                #pragma unroll
                for (int c = 0; c < 7; ++c) { st2[c] = st2[c + 1]; st3[c] = st3[c + 1]; }
                st2[7] = vca / delay * 1e-3f;
                st3[7] = delay * 1e-4f;
                sx[2] = sx[3]; sx[3] = sx[4] * 1e-6f;
                #pragma unroll
                for (int j = 0; j < 6; ++j) st4[j] = sx[4] * (float)(1 << j) * 1e-6f;
            }
        }
        __syncthreads();
    }

    // ---- final eval (step 6): full feat only ----
    if (tid < 128) {
        lfeat[tid]        = relu_(sx[0] * lw0v[tid] + lb0v[tid]);
        lfeat[1920 + tid] =        sx[2] * lw2v[tid] + lb2v[tid];
    } else {
        int j = tid - 128;
        lfeat[128 + j] = relu_(sx[1] * lw1v[j] + lb1v[j]);
    }
    for (int m = tid; m < 640; m += TPB) {
        int c = m / 5, w = m - c * 5;
        float a2 = lcb[c], a3 = lcb[c];
        #pragma unroll
        for (int k = 0; k < 4; ++k) {
            float cw = lcw[c * 4 + k];
            a2 += st2[w + k] * cw;
            a3 += st3[w + k] * cw;
        }
        lfeat[256 + m] = relu_(a2);
        lfeat[896 + m] = relu_(a3);
    }
    for (int m = tid; m < 384; m += TPB) {
        int c = m / 3, w = m - c * 3;
        float a4 = lcb[c];
        #pragma unroll
        for (int k = 0; k < 4; ++k) a4 += st4[w + k] * lcw[c * 4 + k];
        lfeat[1536 + m] = relu_(a4);
    }
    __syncthreads();
    {
        const float4* w4p = (const float4*)wr;
        const float4* f4p = (const float4*)lfeat;
        float4 acc = make_float4(0.f, 0.f, 0.f, 0.f);
        #pragma unroll
        for (int it = 0; it < 8; ++it) {
            float4 a = w4p[it * 64 + lane];
            float4 f = f4p[it * 64 + lane];
            acc.x += a.x * f.x; acc.y += a.y * f.y;
            acc.z += a.z * f.z; acc.w += a.w * f.w;
        }
        float s = (acc.x + acc.y) + (acc.z + acc.w);
        #pragma unroll
        for (int off = 32; off > 0; off >>= 1) s += __shfl_xor(s, off);
        if (lane == 0) h_lds[wv] = relu_(s + bias3);
    }
    __syncthreads();
    if (tid < 6) {
        float p = 0.f;
        #pragma unroll
        for (int w = 0; w < 4; ++w) p += lw4[tid * 128 + b * 4 + w] * h_lds[w];
        __hip_atomic_store(&partials[(3 * NBLK + b) * PSTRIDE + tid], p,
                           __ATOMIC_RELAXED, __HIP_MEMORY_SCOPE_AGENT);
    }
    __syncthreads();
    if (tid == 0)
        __hip_atomic_store(&flags[b * FSTRIDE], 4,
                           __ATOMIC_RELEASE, __HIP_MEMORY_SCOPE_AGENT);
    if (b == 0) {
        if (tid < NBLK) {
            while (__hip_atomic_load(&flags[tid * FSTRIDE], __ATOMIC_ACQUIRE,
                                     __HIP_MEMORY_SCOPE_AGENT) < 4)
                __builtin_amdgcn_s_sleep(1);
        }
        __syncthreads();
        if (tid < 6) {
            float p = lb4v[tid];
            #pragma unroll
            for (int bb = 0; bb < NBLK; ++bb)
                p += __hip_atomic_load(&partials[(3 * NBLK + bb) * PSTRIDE + tid],
                                       __ATOMIC_RELAXED, __HIP_MEMORY_SCOPE_AGENT);
            out[tid] = p;
        }
    }
}

extern "C" void kernel_launch(void* const* d_in, const int* in_sizes, int n_in,
                              void* d_out, int out_size, void* d_ws, size_t ws_size,
                              hipStream_t stream) {
    const float* inp    = (const float*)d_in[0];
    const float* conv_w = (const float*)d_in[1];
    const float* conv_b = (const float*)d_in[2];
    const float* w0     = (const float*)d_in[3];
    const float* b0     = (const float*)d_in[4];
    const float* w1     = (const float*)d_in[5];
    const float* b1     = (const float*)d_in[6];
    const float* w2     = (const float*)d_in[7];
    const float* b2     = (const float*)d_in[8];
    const float* w3     = (const float*)d_in[9];
    const float* b3     = (const float*)d_in[10];
    const float* w4     = (const float*)d_in[11];
    const float* b4     = (const float*)d_in[12];

    int*   flags    = (int*)d_ws;                       // 32 flags, 128 B apart
    float* partials = (float*)((char*)d_ws + 8192);

    actor_kernel<<<NBLK, TPB, 0, stream>>>(inp, conv_w, conv_b,
                                           w0, b0, w1, b1, w2, b2,
                                           w3, b3, w4, b4,
                                           (float*)d_out, flags, partials);
}